// Round 19
// baseline (135.677 us; speedup 1.0000x reference)
//
#include <hip/hip_runtime.h>
#include <math.h>

#define TT 9
#define HH 128
#define WW 128
#define BB 8
#define SLICE (HH*WW)           // 16384
#define CHW (TT*SLICE)          // 147456
#define BCH (2*CHW)             // 294912
#define TOT (BB*BCH)            // 2359296
#define INV_M (1.0f/147456.0f)
#define NYG 32                  // y-groups of 4 rows (accum9 granularity)
#define NBK (9*NYG)             // 288 buckets per batch
#define SEGCAP 4096u            // fixed bucket capacity (mean ~1820, 2.25x)
#define SSCALE 274877906944.0f  // 2^38 fixed-point scale for sum-of-ts
#define INV_SSCALE (1.0/274877906944.0)

// ---------------- K0: bounds + Kc (block 0) / tail-zero + cursors (blk 1) --
__global__ void __launch_bounds__(1024) k_bounds(
        const int* __restrict__ b, int* __restrict__ start, int n,
        const float* __restrict__ conv1_w, const float* __restrict__ dyn_w,
        const float* __restrict__ conv3_w, float* __restrict__ Kc,
        unsigned* __restrict__ tailz, unsigned* __restrict__ cursor, int initCur) {
    if (blockIdx.x == 1) {
        if (threadIdx.x < 72) tailz[threadIdx.x] = 0u;       // gmax + s1 + s2
        if (initCur)
            for (int i = threadIdx.x; i < 8 * NBK; i += 1024)
                cursor[i] = (unsigned)i * SEGCAP;
        return;
    }
    int tid = threadIdx.x;
    if (tid < 9) {
        if (tid == 0) start[0] = 0;
        else if (tid == 8) start[8] = n;
        else {
            int lo = 0, hi = n;
            while (lo < hi) { int mid = (lo + hi) >> 1; if (b[mid] < tid) lo = mid + 1; else hi = mid; }
            start[tid] = lo;
        }
    }
    if (tid >= 32 && tid < 44) {
        int q = tid - 32;             // Kc[o2*6 + c*3 + d]
        int d = q % 3, c = (q / 3) & 1, o2 = q / 6;
        float acc = 0.0f;
        for (int o = 0; o < 16; ++o) {
            float c3 = conv3_w[o2 * 16 + o];
            for (int i = 0; i < 16; ++i) {
                float wsum = 0.0f;
                for (int k = 0; k < 4; ++k) wsum += dyn_w[((k * 16 + o) * 16 + i) * 3 + d];
                acc += c3 * (0.25f * wsum) * conv1_w[i * 2 + c];
                // attention is exactly uniform: pooled mean of inorm output is 0
            }
        }
        Kc[q] = acc;
    }
}

// ---------------- K1: per-batch max of t (float4, 1024 thr) ----------------
__global__ void __launch_bounds__(1024) k_tmax(
        const float* __restrict__ t, const int* __restrict__ start,
        unsigned* __restrict__ gmax) {
    __shared__ unsigned sm[1024];
    int bi = blockIdx.x & 7, cj = blockIdx.x >> 3, nb = gridDim.x >> 3;
    int s = start[bi], e = start[bi + 1];
    unsigned m = 0u;
    if (e > s) {
        int a = (s + 3) & ~3; if (a > e) a = e;
        int z = e & ~3;       if (z < a) z = a;
        if (cj == 0) {       // head/tail scalars (<=3 each)
            int i = s + (int)threadIdx.x;
            if (i < a) { unsigned v = __float_as_uint(t[i]); if (v > m) m = v; }
            i = z + (int)threadIdx.x;
            if (i < e) { unsigned v = __float_as_uint(t[i]); if (v > m) m = v; }
        }
        long nq = (long)(z - a) >> 2;
        long per = (nq + nb - 1) / nb;
        long q0 = (long)cj * per; if (q0 > nq) q0 = nq;
        long q1 = q0 + per;       if (q1 > nq) q1 = nq;
        const float4* tp = (const float4*)(t + a);
        for (long i = q0 + threadIdx.x; i < q1; i += 1024) {
            float4 u = tp[i];
            unsigned c = __float_as_uint(fmaxf(fmaxf(u.x, u.y), fmaxf(u.z, u.w)));
            if (c > m) m = c;    // t>=0: float order == uint order
        }
    }
    sm[threadIdx.x] = m;
    __syncthreads();
    for (int ofs = 512; ofs > 0; ofs >>= 1) {
        if (threadIdx.x < ofs && sm[threadIdx.x + ofs] > sm[threadIdx.x])
            sm[threadIdx.x] = sm[threadIdx.x + ofs];
        __syncthreads();
    }
    if (threadIdx.x == 0 && sm[0]) atomicMax(&gmax[bi], sm[0]);
}

// ---------------- K2: place records — LDS-staged, bucket-sorted writes -----
__global__ void __launch_bounds__(1024) k_place(
        const float* __restrict__ t, const int* __restrict__ x,
        const int* __restrict__ y, const int* __restrict__ p,
        const unsigned* __restrict__ gmax, const int* __restrict__ start,
        unsigned* __restrict__ cursor, int2* __restrict__ rec) {
    __shared__ unsigned lh[NBK], lc[NBK], cbase[NBK];
    __shared__ unsigned wsum[5];
    __shared__ int2 srec[4096];                  // 32 KiB
    __shared__ unsigned short sbkt[4096];        // 8 KiB
    int bi = blockIdx.x & 7, cj = blockIdx.x >> 3, nb = gridDim.x >> 3;
    int s = start[bi], e = start[bi + 1];
    if (e <= s) return;
    float tmax = __uint_as_float(gmax[bi]);
    int a = (s + 3) & ~3; if (a > e) a = e;
    int z = e & ~3;       if (z < a) z = a;
    long nq = (long)(z - a) >> 2;
    long per = (nq + nb - 1) / nb;
    long q0 = (long)cj * per; if (q0 > nq) q0 = nq;
    long q1 = q0 + per;       if (q1 > nq) q1 = nq;
    const float4* tp = (const float4*)(t + a);
    const int4*   xp = (const int4*)(x + a);
    const int4*   yp = (const int4*)(y + a);
    const int4*   pp = (const int4*)(p + a);
    for (long base = q0; base < q1; base += 1024) {   // 1024 quads = 4096 events
        if (threadIdx.x < NBK) lh[threadIdx.x] = 0u;
        __syncthreads();
        long qi = base + threadIdx.x;
        int lb[4]; float tsv[4]; int keyv[4]; unsigned rank[4];
        #pragma unroll
        for (int k = 0; k < 4; ++k) lb[k] = -1;
        if (qi < q1) {
            float4 tv = tp[qi]; int4 xv = xp[qi]; int4 yv = yp[qi]; int4 pv = pp[qi];
            float tq[4] = {tv.x, tv.y, tv.z, tv.w};
            int   xq[4] = {xv.x, xv.y, xv.z, xv.w};
            int   yq[4] = {yv.x, yv.y, yv.z, yv.w};
            int   pq[4] = {pv.x, pv.y, pv.z, pv.w};
            #pragma unroll
            for (int k = 0; k < 4; ++k) {
                float ts = tq[k] / tmax * 9.0f;      // same op order as reference
                int i0 = (int)floorf(ts);
                if ((unsigned)i0 < 9u) {
                    lb[k] = i0 * NYG + (yq[k] >> 2);
                    tsv[k] = ts;
                    keyv[k] = xq[k] + (yq[k] << 7) + (pq[k] << 14);
                }
            }
        }
        #pragma unroll
        for (int k = 0; k < 4; ++k)
            if (lb[k] >= 0) rank[k] = atomicAdd(&lh[lb[k]], 1u);   // count == rank
        __syncthreads();
        // wave-shuffle exclusive scan over 288 counters (5 full waves)
        unsigned v = 0, inc = 0;
        if (threadIdx.x < 320) {
            v = (threadIdx.x < NBK) ? lh[threadIdx.x] : 0u;
            inc = v;
            #pragma unroll
            for (int ofs = 1; ofs < 64; ofs <<= 1) {
                unsigned u = __shfl_up(inc, ofs, 64);
                if ((threadIdx.x & 63) >= ofs) inc += u;
            }
            if ((threadIdx.x & 63) == 63) wsum[threadIdx.x >> 6] = inc;
        }
        __syncthreads();
        if (threadIdx.x < NBK) {
            unsigned ex = inc - v;
            int w = threadIdx.x >> 6;
            for (int j = 0; j < w; ++j) ex += wsum[j];
            cbase[threadIdx.x] = ex;
            lc[threadIdx.x] = v ? atomicAdd(&cursor[bi * NBK + threadIdx.x], v) : 0u;
        }
        __syncthreads();
        // stage records bucket-sorted in LDS (slot < 4096 by construction)
        #pragma unroll
        for (int k = 0; k < 4; ++k)
            if (lb[k] >= 0) {
                unsigned sl_ = cbase[lb[k]] + rank[k];
                srec[sl_] = make_int2(__float_as_int(tsv[k]), keyv[k]);
                sbkt[sl_] = (unsigned short)lb[k];
            }
        __syncthreads();
        // write-out: bucket-sorted slots -> contiguous destination runs
        unsigned tot = cbase[NBK - 1] + lh[NBK - 1];
        #pragma unroll
        for (int h = 0; h < 4; ++h) {
            unsigned slot = threadIdx.x + h * 1024;
            if (slot < tot) {
                int bkt = sbkt[slot];
                unsigned dst = lc[bkt] + (slot - cbase[bkt]);
                if (dst < (unsigned)(bi * NBK + bkt + 1) * SEGCAP)  // capacity guard
                    rec[dst] = srec[slot];
            }
        }
        __syncthreads();   // protect lh/cbase/srec before next chunk
    }
    if (cj == 0) {   // head/tail scalars (<=3 each), direct cursor reserve
        int i = -1;
        if ((int)threadIdx.x < a - s) i = s + threadIdx.x;
        else if (threadIdx.x >= 64 && (int)(threadIdx.x - 64) < e - z) i = z + (threadIdx.x - 64);
        if (i >= 0) {
            float ts = t[i] / tmax * 9.0f;
            int i0 = (int)floorf(ts);
            if ((unsigned)i0 < 9u) {
                int lbx = i0 * NYG + (y[i] >> 2);
                unsigned slot = atomicAdd(&cursor[bi * NBK + lbx], 1u);
                if (slot < (unsigned)(bi * NBK + lbx + 1) * SEGCAP)
                    rec[slot] = make_int2(__float_as_int(ts), x[i] + (y[i] << 7) + (p[i] << 14));
            }
        }
    }
}

// ---------------- K3: {C,S} accum + in-register recon + fused stats --------
// Block (b, yg4): loops t=0..8. One u64 LDS atomic per event; prefix C/S in
// registers; vox written directly. cell = p*512 + (y&3)*128 + x
#define CELL(K) (((K) & 511) | (((K) >> 5) & 512))
#define DEP1(TSB, KEY) { float ts_ = __int_as_float(TSB); \
    unsigned long long sq_ = (unsigned long long)(ts_ * SSCALE); \
    atomicAdd(&asl[CELL(KEY)], (1ull << 48) | sq_); }

__global__ void __launch_bounds__(1024) k_accum9(
        const int2* __restrict__ rec, const unsigned* __restrict__ cursor,
        float* __restrict__ vox, float* __restrict__ s1) {
    __shared__ unsigned long long asl[1024];     // 8 KiB {C,S} tile
    __shared__ float rs[1024], rq[1024];
    int bb = blockIdx.x, yg = blockIdx.y;
    int cell = threadIdx.x;                      // each thread owns one cell
    int pch = cell >> 9, row = (cell >> 7) & 3, xx = cell & 127;
    float* vp = vox + (size_t)bb * BCH + (size_t)pch * CHW
              + (size_t)(((yg << 2) + row) << 7) + xx;
    double Cp = 0.0, Sp = 0.0;
    float ls = 0.f, lq = 0.f;
    for (int t = 0; t < 9; ++t) {
        asl[cell] = 0ull;
        __syncthreads();
        int lb = bb * NBK + t * NYG + yg;
        unsigned s = (unsigned)lb * SEGCAP;
        unsigned e = cursor[lb];                 // = s + len after place
        unsigned cap = s + SEGCAP; if (e > cap) e = cap;
        unsigned a = (s + 1) & ~1u, z = e & ~1u; if (z < a) z = a;
        if (threadIdx.x == 0 && s < a && s < e) { int2 r = rec[s]; DEP1(r.x, r.y) }
        if (threadIdx.x == 1 && z < e)          { int2 r = rec[z]; DEP1(r.x, r.y) }
        int n2 = (int)((z - a) >> 1);
        const int4* rp = (const int4*)(rec + a);
        for (int i = threadIdx.x; i < n2; i += 1024) {
            int4 q = rp[i];
            DEP1(q.x, q.y)
            DEP1(q.z, q.w)
        }
        __syncthreads();
        unsigned long long Av = asl[cell];
        double C = (double)(unsigned)(Av >> 48);
        double S = (double)(Av & 0xFFFFFFFFFFFFull) * INV_SSCALE;
        float v = (float)(C * (double)(1 + t) - S + (Sp - Cp * (double)(t - 1)));
        vp[t * SLICE] = v;
        ls += v; lq += v * v;
        Cp = C; Sp = S;
        __syncthreads();                         // asl reuse next iteration
    }
    rs[threadIdx.x] = ls; rq[threadIdx.x] = lq;
    __syncthreads();
    for (int ofs = 256; ofs > 0; ofs >>= 1) {    // reduce each 512-half (per p)
        if ((threadIdx.x & 511) < ofs) {
            rs[threadIdx.x] += rs[threadIdx.x + ofs];
            rq[threadIdx.x] += rq[threadIdx.x + ofs];
        }
        __syncthreads();
    }
    if (threadIdx.x == 0)   { atomicAdd(&s1[bb * 2],     rs[0]);   atomicAdd(&s1[16 + bb * 2],     rq[0]); }
    if (threadIdx.x == 512) { atomicAdd(&s1[bb * 2 + 1], rs[512]); atomicAdd(&s1[16 + bb * 2 + 1], rq[512]); }
}

// ---------------- K2 fallback: unpacked 9x-rescan, direct vox --------------
__global__ void __launch_bounds__(1024, 4) k_scat(
        const float* __restrict__ t, const int* __restrict__ x,
        const int* __restrict__ y, const int* __restrict__ p,
        const unsigned* __restrict__ gmax, const int* __restrict__ start,
        float* __restrict__ vox) {
    __shared__ float sl[2 * SLICE];
    int tg = blockIdx.x, bb = blockIdx.y;
    int cs = start[bb], ce = start[bb + 1];
    for (int j = threadIdx.x; j < 2 * SLICE; j += 1024) sl[j] = 0.0f;
    __syncthreads();
    float tmax = __uint_as_float(gmax[bb]);
    float ftg = (float)tg;
    for (int i = cs + threadIdx.x; i < ce; i += 1024) {
        float ts = t[i] / tmax * 9.0f;
        float fl = floorf(ts);
        int i0 = (int)fl;
        bool h0 = (i0 == tg), h1 = (i0 + 1 == tg);
        if (h0 | h1) {
            float w = h0 ? (1.0f - (ts - fl)) : (1.0f - (ftg - ts));
            int hw = x[i] + (y[i] << 7) + (p[i] << 14);
            atomicAdd(&sl[hw], w);
        }
    }
    __syncthreads();
    float* dst = vox + (size_t)bb * BCH + (size_t)tg * SLICE;
    for (int j = threadIdx.x; j < SLICE; j += 1024) {
        dst[j]       = sl[j];
        dst[CHW + j] = sl[SLICE + j];
    }
}

// ---------------- K3f: per-(b,c) sum / sumsq of vox (fallback path) --------
__global__ void k_stats1(const float* __restrict__ vox, float* __restrict__ s1) {
    __shared__ float ss[256], sq[256];
    int bc = blockIdx.x >> 5, part = blockIdx.x & 31;
    const float4* vp = (const float4*)(vox + (long)bc * CHW);
    const int per = (CHW / 4) / 32;
    float s = 0.f, q = 0.f;
    for (int j = part * per + threadIdx.x; j < (part + 1) * per; j += 256) {
        float4 v = vp[j];
        s += v.x + v.y + v.z + v.w;
        q += v.x * v.x + v.y * v.y + v.z * v.z + v.w * v.w;
    }
    ss[threadIdx.x] = s; sq[threadIdx.x] = q;
    __syncthreads();
    for (int ofs = 128; ofs > 0; ofs >>= 1) {
        if (threadIdx.x < ofs) { ss[threadIdx.x] += ss[threadIdx.x + ofs]; sq[threadIdx.x] += sq[threadIdx.x + ofs]; }
        __syncthreads();
    }
    if (threadIdx.x == 0) { atomicAdd(&s1[bc], ss[0]); atomicAdd(&s1[16 + bc], sq[0]); }
}

// ---------------- K5: FUSED mask + g (mask never touches global) -----------
// Block (b, o2, yg8): 8-row strip. Phase 1 binarizes the 12-row halo of all
// 9 t-slices of vox[b][o2] into LDS bytes. Phase 2 computes around/mask per
// t in LDS (mask stored as integer s in [0,9]; value (float)s/9.0f is
// bit-identical to the old k_mask). Phase 3 is the old k_g column conv,
// reading mask from LDS and writing g to out once. Saves the 9.4 MB mask
// write + 9.4 MB read and one dispatch.
__global__ void __launch_bounds__(256) k_mg(
        const float* __restrict__ vox, float* __restrict__ out,
        const float* __restrict__ s1, const float* __restrict__ Kc,
        float* __restrict__ s2) {
    __shared__ float snrm[32];
    __shared__ unsigned char sbx[9][12][128];    // 13824 B binarized halo
    __shared__ unsigned char sar[10][128];       // around, reused per t
    __shared__ unsigned char marr[9][8][128];    // mask sums (0..9)
    __shared__ float red[256], red2[256];
    int bb = blockIdx.x, o2 = blockIdx.y, yg = blockIdx.z;   // (8,2,16)
    int y0 = yg << 3;
    if (threadIdx.x < 16) {
        float mm = s1[threadIdx.x] * INV_M;
        float var = s1[16 + threadIdx.x] * INV_M - mm * mm;
        float inv = rsqrtf(var + 1e-5f);
        snrm[threadIdx.x] = inv;
        snrm[16 + threadIdx.x] = -mm * inv;
    }
    const float* vb = vox + (size_t)bb * BCH + (size_t)o2 * CHW;
    // phase 1: binarize rows [y0-2, y0+10) of all 9 slices (zero-pad in y)
    for (int j = threadIdx.x; j < 9 * 12 * 128; j += 256) {
        int xx = j & 127, r = (j >> 7) % 12, tt = j / (12 * 128);
        int gy = y0 - 2 + r;
        sbx[tt][r][xx] = ((unsigned)gy < 128u &&
                          vb[tt * SLICE + (gy << 7) + xx] > 0.0f) ? 1 : 0;
    }
    __syncthreads();
    // phase 2: around + mask per t (exact integer forms)
    for (int tt = 0; tt < 9; ++tt) {
        int tn = (tt + 1 < 9) ? tt + 1 : 8;      // replication pad in T
        for (int j = threadIdx.x; j < 10 * 128; j += 256) {
            int xx = j & 127, ra = j >> 7;
            int gy = y0 - 1 + ra;
            unsigned char v = 0;
            if ((unsigned)gy < 128u) {
                int s = 0;
                for (int rs = ra; rs <= ra + 2; ++rs)
                    for (int dx = -1; dx <= 1; ++dx) {
                        int x2 = xx + dx; if ((unsigned)x2 >= 128u) continue;
                        s += sbx[tt][rs][x2];
                    }
                // prev*bxn > 4/9  <=>  bxn==1 && boxsum >= 5
                v = (sbx[tn][ra + 1][xx] && s >= 5) ? 1 : 0;
            }
            sar[ra][xx] = v;
        }
        __syncthreads();
        for (int j = threadIdx.x; j < 8 * 128; j += 256) {
            int xx = j & 127, q = j >> 7;
            int s = 0;
            for (int ra = q; ra <= q + 2; ++ra)
                for (int dx = -1; dx <= 1; ++dx) {
                    int x2 = xx + dx; if ((unsigned)x2 >= 128u) continue;
                    s += sar[ra][x2];
                }
            marr[tt][q][xx] = (unsigned char)s;
        }
        __syncthreads();                         // sar reuse next t
    }
    // phase 3: g for the strip's 1024 columns (4 per thread)
    float sc0 = snrm[bb * 2], sh0 = snrm[16 + bb * 2];
    float sc1 = snrm[bb * 2 + 1], sh1 = snrm[16 + bb * 2 + 1];
    float k00 = Kc[o2 * 6 + 0], k01 = Kc[o2 * 6 + 1], k02 = Kc[o2 * 6 + 2];
    float k10 = Kc[o2 * 6 + 3], k11 = Kc[o2 * 6 + 4], k12 = Kc[o2 * 6 + 5];
    const float* v0 = vox + (size_t)bb * BCH;    // c=0
    const float* v1 = v0 + CHW;                  // c=1
    float* go = out + (size_t)bb * BCH + (size_t)o2 * CHW;
    float ls = 0.f, lq = 0.f;
    #pragma unroll
    for (int k = 0; k < 4; ++k) {
        int j = threadIdx.x + (k << 8);          // 0..1023
        int q = j >> 7, xx = j & 127;
        int hw = ((y0 + q) << 7) + xx;
        float a[9], d[9];
        #pragma unroll
        for (int tt = 0; tt < 9; ++tt) a[tt] = v0[tt * SLICE + hw] * sc0 + sh0;
        #pragma unroll
        for (int tt = 0; tt < 9; ++tt) d[tt] = v1[tt * SLICE + hw] * sc1 + sh1;
        #pragma unroll
        for (int tt = 0; tt < 9; ++tt) {
            float pre = k01 * a[tt] + k11 * d[tt];
            if (tt > 0) pre += k00 * a[tt - 1] + k10 * d[tt - 1];
            if (tt < 8) pre += k02 * a[tt + 1] + k12 * d[tt + 1];
            float sig = 1.0f / (1.0f + expf(-pre));
            float g = sig * ((float)marr[tt][q][xx] / 9.0f);
            go[tt * SLICE + hw] = g;
            ls += g; lq += g * g;
        }
    }
    red[threadIdx.x] = ls; red2[threadIdx.x] = lq;
    __syncthreads();
    for (int ofs = 128; ofs > 0; ofs >>= 1) {
        if (threadIdx.x < ofs) { red[threadIdx.x] += red[threadIdx.x + ofs]; red2[threadIdx.x] += red2[threadIdx.x + ofs]; }
        __syncthreads();
    }
    if (threadIdx.x == 0) {
        int bc = bb * 2 + o2;
        atomicAdd(&s2[bc], red[0]); atomicAdd(&s2[16 + bc], red2[0]);
    }
}

// ---------------- K7: final instance norm in place (float4) ----------------
__global__ void k_norm(float* __restrict__ out, const float* __restrict__ s2) {
    int i4 = blockIdx.x * 256 + threadIdx.x;    // grid = TOT/1024
    int bc = i4 / (CHW / 4);
    float m = s2[bc] * INV_M;
    float var = s2[16 + bc] * INV_M - m * m;
    float inv = rsqrtf(var + 1e-5f);
    float4 v = ((float4*)out)[i4];
    v.x = (v.x - m) * inv; v.y = (v.y - m) * inv;
    v.z = (v.z - m) * inv; v.w = (v.w - m) * inv;
    ((float4*)out)[i4] = v;
}

extern "C" void kernel_launch(void* const* d_in, const int* in_sizes, int n_in,
                              void* d_out, int out_size, void* d_ws, size_t ws_size,
                              hipStream_t stream) {
    const float* t  = (const float*)d_in[0];
    const int*   x  = (const int*)d_in[1];
    const int*   y  = (const int*)d_in[2];
    const int*   p  = (const int*)d_in[3];
    const int*   b  = (const int*)d_in[4];
    const float* conv1_w = (const float*)d_in[5];
    // d_in[6], d_in[7] (fc1_w, fc2_w): unused — attention is exactly uniform
    const float* dyn_w   = (const float*)d_in[8];
    const float* conv3_w = (const float*)d_in[9];
    float* out = (float*)d_out;
    int n = in_sizes[0];

    const long RECF = 2L * 8 * NBK * SEGCAP;     // rec floats: 2304*4096 int2
    long availF = (long)(ws_size / sizeof(float));
    long need = (long)TOT + RECF + 8192;
    int useBuckets = (availF >= need);

    float* ws   = (float*)d_ws;
    float* vox  = ws;                                        // TOT
    int2*  rec  = (int2*)(ws + TOT);                         // 2304*4096 records
    float* tail = ws + TOT + (useBuckets ? RECF : 0);
    // zeroed in k_bounds block 1: gmax(8) s1(32) s2(32) = 72
    unsigned* gmax    = (unsigned*)tail;                     // +0
    float*    s1      = tail + 8;                            // +8
    float*    s2      = tail + 40;                           // +40
    // non-zeroed:
    float*    Kc      = tail + 72;                           // +72  (12)
    int*      start   = (int*)(tail + 84);                   // +84  (12)
    unsigned* cursor  = (unsigned*)(tail + 96);              // +96  (2304)

    k_bounds<<<2, 1024, 0, stream>>>(b, start, n, conv1_w, dyn_w, conv3_w, Kc,
                                     (unsigned*)tail, cursor, useBuckets);
    k_tmax<<<256, 1024, 0, stream>>>(t, start, gmax);
    if (useBuckets) {
        k_place<<<512, 1024, 0, stream>>>(t, x, y, p, gmax, start, cursor, rec);
        k_accum9<<<dim3(8, NYG), 1024, 0, stream>>>(rec, cursor, vox, s1);
    } else {
        k_scat<<<dim3(9, 8, 1), 1024, 0, stream>>>(t, x, y, p, gmax, start, vox);
        k_stats1<<<512, 256, 0, stream>>>(vox, s1);
    }
    k_mg<<<dim3(8, 2, 16), 256, 0, stream>>>(vox, out, s1, Kc, s2);
    k_norm<<<TOT / 1024, 256, 0, stream>>>(out, s2);
}

// Round 20
// 125.696 us; speedup vs baseline: 1.0794x; 1.0794x over previous
//
#include <hip/hip_runtime.h>
#include <math.h>

#define TT 9
#define HH 128
#define WW 128
#define BB 8
#define SLICE (HH*WW)           // 16384
#define CHW (TT*SLICE)          // 147456
#define BCH (2*CHW)             // 294912
#define TOT (BB*BCH)            // 2359296
#define INV_M (1.0f/147456.0f)
#define NYG 32                  // y-groups of 4 rows
#define NBK (9*NYG)             // 288 buckets per batch
#define SEGCAP 4096u            // fixed bucket capacity (mean ~1820, 2.25x)
#define SSCALE 274877906944.0f  // 2^38 fixed-point scale for sum-of-ts
#define INV_SSCALE (1.0/274877906944.0)

// ---------------- K0: bounds + Kc (block 0) / tail-zero + cursors (blk 1) --
// In-graph hipMemsetAsync removed: a 288-byte fill kernel measured ~39 us
// fixed overhead per replay; zeroing here is free.
__global__ void __launch_bounds__(1024) k_bounds(
        const int* __restrict__ b, int* __restrict__ start, int n,
        const float* __restrict__ conv1_w, const float* __restrict__ dyn_w,
        const float* __restrict__ conv3_w, float* __restrict__ Kc,
        unsigned* __restrict__ tailz, unsigned* __restrict__ cursor, int initCur) {
    if (blockIdx.x == 1) {
        if (threadIdx.x < 72) tailz[threadIdx.x] = 0u;       // gmax + s1 + s2
        if (initCur)
            for (int i = threadIdx.x; i < 8 * NBK; i += 1024)
                cursor[i] = (unsigned)i * SEGCAP;
        return;
    }
    int tid = threadIdx.x;
    if (tid < 9) {
        if (tid == 0) start[0] = 0;
        else if (tid == 8) start[8] = n;
        else {
            int lo = 0, hi = n;
            while (lo < hi) { int mid = (lo + hi) >> 1; if (b[mid] < tid) lo = mid + 1; else hi = mid; }
            start[tid] = lo;
        }
    }
    if (tid >= 32 && tid < 44) {
        int q = tid - 32;             // Kc[o2*6 + c*3 + d]
        int d = q % 3, c = (q / 3) & 1, o2 = q / 6;
        float acc = 0.0f;
        for (int o = 0; o < 16; ++o) {
            float c3 = conv3_w[o2 * 16 + o];
            for (int i = 0; i < 16; ++i) {
                float wsum = 0.0f;
                for (int k = 0; k < 4; ++k) wsum += dyn_w[((k * 16 + o) * 16 + i) * 3 + d];
                acc += c3 * (0.25f * wsum) * conv1_w[i * 2 + c];
                // attention is exactly uniform: pooled mean of inorm output is 0
            }
        }
        Kc[q] = acc;
    }
}

// ---------------- K1: per-batch max of t (float4, 1024 thr) ----------------
__global__ void __launch_bounds__(1024) k_tmax(
        const float* __restrict__ t, const int* __restrict__ start,
        unsigned* __restrict__ gmax) {
    __shared__ unsigned sm[1024];
    int bi = blockIdx.x & 7, cj = blockIdx.x >> 3, nb = gridDim.x >> 3;
    int s = start[bi], e = start[bi + 1];
    unsigned m = 0u;
    if (e > s) {
        int a = (s + 3) & ~3; if (a > e) a = e;
        int z = e & ~3;       if (z < a) z = a;
        if (cj == 0) {       // head/tail scalars (<=3 each)
            int i = s + (int)threadIdx.x;
            if (i < a) { unsigned v = __float_as_uint(t[i]); if (v > m) m = v; }
            i = z + (int)threadIdx.x;
            if (i < e) { unsigned v = __float_as_uint(t[i]); if (v > m) m = v; }
        }
        long nq = (long)(z - a) >> 2;
        long per = (nq + nb - 1) / nb;
        long q0 = (long)cj * per; if (q0 > nq) q0 = nq;
        long q1 = q0 + per;       if (q1 > nq) q1 = nq;
        const float4* tp = (const float4*)(t + a);
        for (long i = q0 + threadIdx.x; i < q1; i += 1024) {
            float4 u = tp[i];
            unsigned c = __float_as_uint(fmaxf(fmaxf(u.x, u.y), fmaxf(u.z, u.w)));
            if (c > m) m = c;    // t>=0: float order == uint order
        }
    }
    sm[threadIdx.x] = m;
    __syncthreads();
    for (int ofs = 512; ofs > 0; ofs >>= 1) {
        if (threadIdx.x < ofs && sm[threadIdx.x + ofs] > sm[threadIdx.x])
            sm[threadIdx.x] = sm[threadIdx.x + ofs];
        __syncthreads();
    }
    if (threadIdx.x == 0 && sm[0]) atomicMax(&gmax[bi], sm[0]);
}

// ---------------- K2: place records — LDS-staged, bucket-sorted writes -----
// Per chunk of 1024 quads (= 4096 events, == staging capacity): rank via
// counting atomic; wave-shuffle exclusive scan of lh (288 counters, 5 waves)
// gives per-chunk bucket bases; records staged bucket-sorted in LDS;
// write-out emits ~288 contiguous runs (~14 recs each), not random 8B stores.
__global__ void __launch_bounds__(1024) k_place(
        const float* __restrict__ t, const int* __restrict__ x,
        const int* __restrict__ y, const int* __restrict__ p,
        const unsigned* __restrict__ gmax, const int* __restrict__ start,
        unsigned* __restrict__ cursor, int2* __restrict__ rec) {
    __shared__ unsigned lh[NBK], lc[NBK], cbase[NBK];
    __shared__ unsigned wsum[5];
    __shared__ int2 srec[4096];                  // 32 KiB
    __shared__ unsigned short sbkt[4096];        // 8 KiB
    int bi = blockIdx.x & 7, cj = blockIdx.x >> 3, nb = gridDim.x >> 3;
    int s = start[bi], e = start[bi + 1];
    if (e <= s) return;
    float tmax = __uint_as_float(gmax[bi]);
    int a = (s + 3) & ~3; if (a > e) a = e;
    int z = e & ~3;       if (z < a) z = a;
    long nq = (long)(z - a) >> 2;
    long per = (nq + nb - 1) / nb;
    long q0 = (long)cj * per; if (q0 > nq) q0 = nq;
    long q1 = q0 + per;       if (q1 > nq) q1 = nq;
    const float4* tp = (const float4*)(t + a);
    const int4*   xp = (const int4*)(x + a);
    const int4*   yp = (const int4*)(y + a);
    const int4*   pp = (const int4*)(p + a);
    for (long base = q0; base < q1; base += 1024) {   // 1024 quads = 4096 events
        if (threadIdx.x < NBK) lh[threadIdx.x] = 0u;
        __syncthreads();
        long qi = base + threadIdx.x;
        int lb[4]; float tsv[4]; int keyv[4]; unsigned rank[4];
        #pragma unroll
        for (int k = 0; k < 4; ++k) lb[k] = -1;
        if (qi < q1) {
            float4 tv = tp[qi]; int4 xv = xp[qi]; int4 yv = yp[qi]; int4 pv = pp[qi];
            float tq[4] = {tv.x, tv.y, tv.z, tv.w};
            int   xq[4] = {xv.x, xv.y, xv.z, xv.w};
            int   yq[4] = {yv.x, yv.y, yv.z, yv.w};
            int   pq[4] = {pv.x, pv.y, pv.z, pv.w};
            #pragma unroll
            for (int k = 0; k < 4; ++k) {
                float ts = tq[k] / tmax * 9.0f;      // same op order as reference
                int i0 = (int)floorf(ts);
                if ((unsigned)i0 < 9u) {
                    lb[k] = i0 * NYG + (yq[k] >> 2);
                    tsv[k] = ts;
                    keyv[k] = xq[k] + (yq[k] << 7) + (pq[k] << 14);
                }
            }
        }
        #pragma unroll
        for (int k = 0; k < 4; ++k)
            if (lb[k] >= 0) rank[k] = atomicAdd(&lh[lb[k]], 1u);   // count == rank
        __syncthreads();
        // wave-shuffle exclusive scan over 288 counters (5 full waves)
        unsigned v = 0, inc = 0;
        if (threadIdx.x < 320) {
            v = (threadIdx.x < NBK) ? lh[threadIdx.x] : 0u;
            inc = v;
            #pragma unroll
            for (int ofs = 1; ofs < 64; ofs <<= 1) {
                unsigned u = __shfl_up(inc, ofs, 64);
                if ((threadIdx.x & 63) >= ofs) inc += u;
            }
            if ((threadIdx.x & 63) == 63) wsum[threadIdx.x >> 6] = inc;
        }
        __syncthreads();
        if (threadIdx.x < NBK) {
            unsigned ex = inc - v;
            int w = threadIdx.x >> 6;
            for (int j = 0; j < w; ++j) ex += wsum[j];
            cbase[threadIdx.x] = ex;
            lc[threadIdx.x] = v ? atomicAdd(&cursor[bi * NBK + threadIdx.x], v) : 0u;
        }
        __syncthreads();
        // stage records bucket-sorted in LDS (slot < 4096 by construction)
        #pragma unroll
        for (int k = 0; k < 4; ++k)
            if (lb[k] >= 0) {
                unsigned sl_ = cbase[lb[k]] + rank[k];
                srec[sl_] = make_int2(__float_as_int(tsv[k]), keyv[k]);
                sbkt[sl_] = (unsigned short)lb[k];
            }
        __syncthreads();
        // write-out: bucket-sorted slots -> contiguous destination runs
        unsigned tot = cbase[NBK - 1] + lh[NBK - 1];
        #pragma unroll
        for (int h = 0; h < 4; ++h) {
            unsigned slot = threadIdx.x + h * 1024;
            if (slot < tot) {
                int bkt = sbkt[slot];
                unsigned dst = lc[bkt] + (slot - cbase[bkt]);
                if (dst < (unsigned)(bi * NBK + bkt + 1) * SEGCAP)  // capacity guard
                    rec[dst] = srec[slot];
            }
        }
        __syncthreads();   // protect lh/cbase/srec before next chunk
    }
    if (cj == 0) {   // head/tail scalars (<=3 each), direct cursor reserve
        int i = -1;
        if ((int)threadIdx.x < a - s) i = s + threadIdx.x;
        else if (threadIdx.x >= 64 && (int)(threadIdx.x - 64) < e - z) i = z + (threadIdx.x - 64);
        if (i >= 0) {
            float ts = t[i] / tmax * 9.0f;
            int i0 = (int)floorf(ts);
            if ((unsigned)i0 < 9u) {
                int lbx = i0 * NYG + (y[i] >> 2);
                unsigned slot = atomicAdd(&cursor[bi * NBK + lbx], 1u);
                if (slot < (unsigned)(bi * NBK + lbx + 1) * SEGCAP)
                    rec[slot] = make_int2(__float_as_int(ts), x[i] + (y[i] << 7) + (p[i] << 14));
            }
        }
    }
}

// ---------------- K3: {C,S} accum + in-register recon + fused stats --------
// Block (b, yg): loops t=0..8. Per t: scatter bucket (b,t,yg) into an 8 KB
// LDS {C,S} tile (count bits[48:63], sum-of-ts fp2^-38 bits[0:47]; ONE u64
// atomic per event), then each thread (owning ONE cell) computes
//   vox[t] = C*(1+t) - S + (Sp - Cp*(t-1))
// with Cp/Sp kept in REGISTERS across t — the A-buffer never exists in
// global memory. cell = p*512 + (y&3)*128 + x
#define CELL(K) (((K) & 511) | (((K) >> 5) & 512))
#define DEP1(TSB, KEY) { float ts_ = __int_as_float(TSB); \
    unsigned long long sq_ = (unsigned long long)(ts_ * SSCALE); \
    atomicAdd(&asl[CELL(KEY)], (1ull << 48) | sq_); }

__global__ void __launch_bounds__(1024) k_accum9(
        const int2* __restrict__ rec, const unsigned* __restrict__ cursor,
        float* __restrict__ vox, float* __restrict__ s1) {
    __shared__ unsigned long long asl[1024];     // 8 KiB {C,S} tile
    __shared__ float rs[1024], rq[1024];
    int bb = blockIdx.x, yg = blockIdx.y;
    int cell = threadIdx.x;                      // each thread owns one cell
    int pch = cell >> 9, row = (cell >> 7) & 3, xx = cell & 127;
    float* vp = vox + (size_t)bb * BCH + (size_t)pch * CHW
              + (size_t)(((yg << 2) + row) << 7) + xx;
    double Cp = 0.0, Sp = 0.0;
    float ls = 0.f, lq = 0.f;
    for (int t = 0; t < 9; ++t) {
        asl[cell] = 0ull;
        __syncthreads();
        int lb = bb * NBK + t * NYG + yg;
        unsigned s = (unsigned)lb * SEGCAP;
        unsigned e = cursor[lb];                 // = s + len after place
        unsigned cap = s + SEGCAP; if (e > cap) e = cap;
        unsigned a = (s + 1) & ~1u, z = e & ~1u; if (z < a) z = a;
        if (threadIdx.x == 0 && s < a && s < e) { int2 r = rec[s]; DEP1(r.x, r.y) }
        if (threadIdx.x == 1 && z < e)          { int2 r = rec[z]; DEP1(r.x, r.y) }
        int n2 = (int)((z - a) >> 1);
        const int4* rp = (const int4*)(rec + a);
        for (int i = threadIdx.x; i < n2; i += 1024) {
            int4 q = rp[i];
            DEP1(q.x, q.y)
            DEP1(q.z, q.w)
        }
        __syncthreads();
        unsigned long long Av = asl[cell];
        double C = (double)(unsigned)(Av >> 48);
        double S = (double)(Av & 0xFFFFFFFFFFFFull) * INV_SSCALE;
        float v = (float)(C * (double)(1 + t) - S + (Sp - Cp * (double)(t - 1)));
        vp[t * SLICE] = v;
        ls += v; lq += v * v;
        Cp = C; Sp = S;
        __syncthreads();                         // asl reuse next iteration
    }
    rs[threadIdx.x] = ls; rq[threadIdx.x] = lq;
    __syncthreads();
    for (int ofs = 256; ofs > 0; ofs >>= 1) {    // reduce each 512-half (per p)
        if ((threadIdx.x & 511) < ofs) {
            rs[threadIdx.x] += rs[threadIdx.x + ofs];
            rq[threadIdx.x] += rq[threadIdx.x + ofs];
        }
        __syncthreads();
    }
    if (threadIdx.x == 0)   { atomicAdd(&s1[bb * 2],     rs[0]);   atomicAdd(&s1[16 + bb * 2],     rq[0]); }
    if (threadIdx.x == 512) { atomicAdd(&s1[bb * 2 + 1], rs[512]); atomicAdd(&s1[16 + bb * 2 + 1], rq[512]); }
}

// ---------------- K2 fallback: unpacked 9x-rescan, direct vox --------------
__global__ void __launch_bounds__(1024, 4) k_scat(
        const float* __restrict__ t, const int* __restrict__ x,
        const int* __restrict__ y, const int* __restrict__ p,
        const unsigned* __restrict__ gmax, const int* __restrict__ start,
        float* __restrict__ vox) {
    __shared__ float sl[2 * SLICE];
    int tg = blockIdx.x, bb = blockIdx.y;
    int cs = start[bb], ce = start[bb + 1];
    for (int j = threadIdx.x; j < 2 * SLICE; j += 1024) sl[j] = 0.0f;
    __syncthreads();
    float tmax = __uint_as_float(gmax[bb]);
    float ftg = (float)tg;
    for (int i = cs + threadIdx.x; i < ce; i += 1024) {
        float ts = t[i] / tmax * 9.0f;
        float fl = floorf(ts);
        int i0 = (int)fl;
        bool h0 = (i0 == tg), h1 = (i0 + 1 == tg);
        if (h0 | h1) {
            float w = h0 ? (1.0f - (ts - fl)) : (1.0f - (ftg - ts));
            int hw = x[i] + (y[i] << 7) + (p[i] << 14);
            atomicAdd(&sl[hw], w);
        }
    }
    __syncthreads();
    float* dst = vox + (size_t)bb * BCH + (size_t)tg * SLICE;
    for (int j = threadIdx.x; j < SLICE; j += 1024) {
        dst[j]       = sl[j];
        dst[CHW + j] = sl[SLICE + j];
    }
}

// ---------------- K3f: per-(b,c) sum / sumsq of vox (fallback path) --------
__global__ void k_stats1(const float* __restrict__ vox, float* __restrict__ s1) {
    __shared__ float ss[256], sq[256];
    int bc = blockIdx.x >> 5, part = blockIdx.x & 31;
    const float4* vp = (const float4*)(vox + (long)bc * CHW);
    const int per = (CHW / 4) / 32;
    float s = 0.f, q = 0.f;
    for (int j = part * per + threadIdx.x; j < (part + 1) * per; j += 256) {
        float4 v = vp[j];
        s += v.x + v.y + v.z + v.w;
        q += v.x * v.x + v.y * v.y + v.z * v.z + v.w * v.w;
    }
    ss[threadIdx.x] = s; sq[threadIdx.x] = q;
    __syncthreads();
    for (int ofs = 128; ofs > 0; ofs >>= 1) {
        if (threadIdx.x < ofs) { ss[threadIdx.x] += ss[threadIdx.x + ofs]; sq[threadIdx.x] += sq[threadIdx.x + ofs]; }
        __syncthreads();
    }
    if (threadIdx.x == 0) { atomicAdd(&s1[bc], ss[0]); atomicAdd(&s1[16 + bc], sq[0]); }
}

// ---------------- K5: time-corr mask ---------------------------------------
#define STRIP 32
__global__ void k_mask(const float* __restrict__ vox, float* __restrict__ mask) {
    __shared__ unsigned char sbx[36 * 128];
    __shared__ unsigned char sar[34 * 128];
    int bid = blockIdx.x;                  // 576 = 8*2*9*4
    int strip = bid & 3;
    int t = (bid >> 2) % 9;
    int c = (bid / 36) & 1;
    int bb = bid / 72;
    long off = (long)bb * BCH + (long)c * CHW;
    const float* vt = vox + off + (long)t * SLICE;
    int tn = (t + 1 < 9) ? t + 1 : 8;      // replication pad in T
    const float* vn = vox + off + (long)tn * SLICE;
    int y0 = strip * STRIP;
    for (int j = threadIdx.x; j < 36 * 128; j += 256) {
        int r = j >> 7, xx = j & 127;
        int gy = y0 - 2 + r;
        sbx[j] = ((unsigned)gy < 128u && vt[(gy << 7) + xx] > 0.0f) ? 1 : 0;
    }
    __syncthreads();
    for (int j = threadIdx.x; j < 34 * 128; j += 256) {
        int ra = j >> 7, xx = j & 127;
        int gy = y0 - 1 + ra;
        unsigned char v = 0;
        if ((unsigned)gy < 128u) {
            int s = 0;
            for (int rs = ra; rs <= ra + 2; ++rs)
                for (int dx = -1; dx <= 1; ++dx) {
                    int x2 = xx + dx; if ((unsigned)x2 >= 128u) continue;
                    s += sbx[(rs << 7) + x2];
                }
            // prev*bxn > 4/9  <=>  bxn==1 && boxsum >= 5  (exact integer form)
            v = (vn[(gy << 7) + xx] > 0.0f && s >= 5) ? 1 : 0;
        }
        sar[j] = v;
    }
    __syncthreads();
    float* mt = mask + off + (long)t * SLICE;
    for (int j = threadIdx.x; j < STRIP * 128; j += 256) {
        int q = j >> 7, xx = j & 127;
        int s = 0;
        for (int ra = q; ra <= q + 2; ++ra)
            for (int dx = -1; dx <= 1; ++dx) {
                int x2 = xx + dx; if ((unsigned)x2 >= 128u) continue;
                s += sar[(ra << 7) + x2];
            }
        mt[((y0 + q) << 7) + xx] = (float)s / 9.0f;
    }
}

// ---------------- K6: whole t-column per thread (nrm folded in) ------------
__global__ void __launch_bounds__(256) k_g(
        const float* __restrict__ vox, float* __restrict__ gm,
        const float* __restrict__ s1, const float* __restrict__ Kc,
        float* __restrict__ s2) {
    __shared__ float snrm[32];
    if (threadIdx.x < 16) {
        float mm = s1[threadIdx.x] * INV_M;
        float var = s1[16 + threadIdx.x] * INV_M - mm * mm;
        float inv = rsqrtf(var + 1e-5f);
        snrm[threadIdx.x] = inv;
        snrm[16 + threadIdx.x] = -mm * inv;
    }
    __syncthreads();
    int idx = blockIdx.x * 256 + threadIdx.x;   // (b,o2,hw): 8*2*16384 threads
    int hw = idx & (SLICE - 1);
    int o2 = (idx >> 14) & 1;
    int bb = idx >> 15;
    const float* v0 = vox + (size_t)bb * BCH + hw;       // c=0 column
    const float* v1 = v0 + CHW;                          // c=1 column
    float* go = gm + (size_t)bb * BCH + (size_t)o2 * CHW + hw;
    float a[9], d[9], m[9];
    #pragma unroll
    for (int tt = 0; tt < 9; ++tt) a[tt] = v0[tt * SLICE];
    #pragma unroll
    for (int tt = 0; tt < 9; ++tt) d[tt] = v1[tt * SLICE];
    #pragma unroll
    for (int tt = 0; tt < 9; ++tt) m[tt] = go[tt * SLICE];
    float sc0 = snrm[bb * 2], sh0 = snrm[16 + bb * 2];
    float sc1 = snrm[bb * 2 + 1], sh1 = snrm[16 + bb * 2 + 1];
    float k00 = Kc[o2 * 6 + 0], k01 = Kc[o2 * 6 + 1], k02 = Kc[o2 * 6 + 2];
    float k10 = Kc[o2 * 6 + 3], k11 = Kc[o2 * 6 + 4], k12 = Kc[o2 * 6 + 5];
    #pragma unroll
    for (int tt = 0; tt < 9; ++tt) { a[tt] = a[tt] * sc0 + sh0; d[tt] = d[tt] * sc1 + sh1; }
    float ls = 0.f, lq = 0.f;
    #pragma unroll
    for (int tt = 0; tt < 9; ++tt) {
        float pre = k01 * a[tt] + k11 * d[tt];
        if (tt > 0) pre += k00 * a[tt - 1] + k10 * d[tt - 1];
        if (tt < 8) pre += k02 * a[tt + 1] + k12 * d[tt + 1];
        float sig = 1.0f / (1.0f + expf(-pre));
        float g = sig * m[tt];
        go[tt * SLICE] = g;
        ls += g; lq += g * g;
    }
    __shared__ float ss[256], sq[256];
    ss[threadIdx.x] = ls; sq[threadIdx.x] = lq;
    __syncthreads();
    for (int ofs = 128; ofs > 0; ofs >>= 1) {
        if (threadIdx.x < ofs) { ss[threadIdx.x] += ss[threadIdx.x + ofs]; sq[threadIdx.x] += sq[threadIdx.x + ofs]; }
        __syncthreads();
    }
    if (threadIdx.x == 0) {
        int bc = bb * 2 + o2;
        atomicAdd(&s2[bc], ss[0]); atomicAdd(&s2[16 + bc], sq[0]);
    }
}

// ---------------- K7: final instance norm in place (float4) ----------------
__global__ void k_norm(float* __restrict__ out, const float* __restrict__ s2) {
    int i4 = blockIdx.x * 256 + threadIdx.x;    // grid = TOT/1024
    int bc = i4 / (CHW / 4);
    float m = s2[bc] * INV_M;
    float var = s2[16 + bc] * INV_M - m * m;
    float inv = rsqrtf(var + 1e-5f);
    float4 v = ((float4*)out)[i4];
    v.x = (v.x - m) * inv; v.y = (v.y - m) * inv;
    v.z = (v.z - m) * inv; v.w = (v.w - m) * inv;
    ((float4*)out)[i4] = v;
}

extern "C" void kernel_launch(void* const* d_in, const int* in_sizes, int n_in,
                              void* d_out, int out_size, void* d_ws, size_t ws_size,
                              hipStream_t stream) {
    const float* t  = (const float*)d_in[0];
    const int*   x  = (const int*)d_in[1];
    const int*   y  = (const int*)d_in[2];
    const int*   p  = (const int*)d_in[3];
    const int*   b  = (const int*)d_in[4];
    const float* conv1_w = (const float*)d_in[5];
    // d_in[6], d_in[7] (fc1_w, fc2_w): unused — attention is exactly uniform
    const float* dyn_w   = (const float*)d_in[8];
    const float* conv3_w = (const float*)d_in[9];
    float* out = (float*)d_out;
    int n = in_sizes[0];

    const long RECF = 2L * 8 * NBK * SEGCAP;     // rec floats: 2304*4096 int2
    long availF = (long)(ws_size / sizeof(float));
    long need = (long)TOT + RECF + 8192;
    int useBuckets = (availF >= need);

    float* ws   = (float*)d_ws;
    float* vox  = ws;                                        // TOT
    int2*  rec  = (int2*)(ws + TOT);                         // 2304*4096 records
    float* tail = ws + TOT + (useBuckets ? RECF : 0);
    // zeroed in k_bounds block 1: gmax(8) s1(32) s2(32) = 72
    unsigned* gmax    = (unsigned*)tail;                     // +0
    float*    s1      = tail + 8;                            // +8
    float*    s2      = tail + 40;                           // +40
    // non-zeroed:
    float*    Kc      = tail + 72;                           // +72  (12)
    int*      start   = (int*)(tail + 84);                   // +84  (12)
    unsigned* cursor  = (unsigned*)(tail + 96);              // +96  (2304)

    k_bounds<<<2, 1024, 0, stream>>>(b, start, n, conv1_w, dyn_w, conv3_w, Kc,
                                     (unsigned*)tail, cursor, useBuckets);
    k_tmax<<<256, 1024, 0, stream>>>(t, start, gmax);
    if (useBuckets) {
        k_place<<<512, 1024, 0, stream>>>(t, x, y, p, gmax, start, cursor, rec);
        k_accum9<<<dim3(8, NYG), 1024, 0, stream>>>(rec, cursor, vox, s1);
    } else {
        k_scat<<<dim3(9, 8, 1), 1024, 0, stream>>>(t, x, y, p, gmax, start, vox);
        k_stats1<<<512, 256, 0, stream>>>(vox, s1);
    }
    k_mask<<<576, 256, 0, stream>>>(vox, out);               // d_out holds mask
    k_g<<<1024, 256, 0, stream>>>(vox, out, s1, Kc, s2);
    k_norm<<<TOT / 1024, 256, 0, stream>>>(out, s2);
}